// Round 8
// baseline (116.382 us; speedup 1.0000x reference)
//
#include <hip/hip_runtime.h>
#include <hip/hip_cooperative_groups.h>

namespace cg = cooperative_groups;

// Consistent-loss, SINGLE cooperative dispatch:
//   256 blocks (one per up-column j) x 256 threads (one per row i):
//   LDS scatter-max into 51 value buckets per side, masked |diff| sums vs
//   left/right row j, wave-0 reduce -> ws[j]; grid.sync(); block 0 sums the
//   256 partials and stores sum/65536 to d_out. No memset, no init deps.
//
// Geometry hard-coded: H=W=256, row split at 128, bucket=round(up*50+110)
// in [110,160] (51 slots), mask up >= 0.0235, threshold 0.2.

__global__ __launch_bounds__(256) void consist_coop_kernel(
    const float* __restrict__ up,
    const float* __restrict__ left,
    const float* __restrict__ right,
    float* __restrict__ ws,
    float* __restrict__ out) {
#pragma clang fp contract(off)
    const int j = blockIdx.x;    // column of `up` == output row of up2{l,r}
    const int t = threadIdx.x;   // row index i

    __shared__ int u2r[64];      // slots 0..50 hold float bits (nonneg -> int order == float order)
    __shared__ int u2l[64];

    if (t < 64) { u2r[t] = 0; u2l[t] = 0; }
    __syncthreads();

    // ---- Phase A: scatter-max over rows i of column j ----
    const float u = up[t * 256 + j];
    if (u >= 0.0235f) {
        // match XLA: mul then add (no FMA), then round-half-even
        float s = u * 50.0f;
        s = s + 110.0f;
        const int b = (int)rintf(s) - 110;   // 0..50
        if (t > 128) {
            const float v = (float)(t - 128) / 60.0f;   // val_r > 0
            atomicMax(&u2r[b], __float_as_int(v));
        } else if (t < 128) {
            const float v = (float)(128 - t) / 60.0f;   // val_l > 0
            atomicMax(&u2l[b], __float_as_int(v));
        }
        // t == 128: val_l == 0 -> no-op against zero-init buffer
    }
    __syncthreads();

    // ---- Phase B: masked |diff| sums at row j, cols 110..160 ----
    float part = 0.0f;
    if (t < 51) {
        const int c = 110 + t;
        const float ur = __int_as_float(u2r[t]);
        if (ur != 0.0f) {
            const float d = fabsf(ur - right[j * 256 + c]);
            if (d < 0.2f) part += d;
        }
        const float ul = __int_as_float(u2l[t]);
        if (ul != 0.0f) {
            const float d = fabsf(ul - left[j * 256 + c]);
            if (d < 0.2f) part += d;
        }
    }

    // ---- wave-0 reduction (all nonzero parts live in lanes 0..50) ----
    if (t < 64) {
        part += __shfl_down(part, 32);
        part += __shfl_down(part, 16);
        part += __shfl_down(part, 8);
        part += __shfl_down(part, 4);
        part += __shfl_down(part, 2);
        part += __shfl_down(part, 1);
        if (t == 0) ws[j] = part;            // unscaled block partial
    }

    // ---- grid-wide rendezvous, then block 0 finishes ----
    __threadfence();                         // make ws[j] device-visible
    cg::this_grid().sync();

    if (blockIdx.x == 0 && t < 64) {
        const float4 v = ((const float4*)ws)[t];   // 64 lanes x 4 = 256 partials
        float s = (v.x + v.y) + (v.z + v.w);
        s += __shfl_down(s, 32);
        s += __shfl_down(s, 16);
        s += __shfl_down(s, 8);
        s += __shfl_down(s, 4);
        s += __shfl_down(s, 2);
        s += __shfl_down(s, 1);
        if (t == 0)
            out[0] = s * (1.0f / 65536.0f);  // mean_r + mean_l, exact pow2 scale
    }
}

extern "C" void kernel_launch(void* const* d_in, const int* in_sizes, int n_in,
                              void* d_out, int out_size, void* d_ws, size_t ws_size,
                              hipStream_t stream) {
    const float* up    = (const float*)d_in[0];
    const float* left  = (const float*)d_in[1];
    const float* right = (const float*)d_in[2];
    float* ws  = (float*)d_ws;
    float* out = (float*)d_out;

    void* args[] = {(void*)&up, (void*)&left, (void*)&right, (void*)&ws, (void*)&out};
    hipLaunchCooperativeKernel((const void*)consist_coop_kernel,
                               dim3(256), dim3(256), args, 0, stream);
}